// Round 11
// baseline (506.759 us; speedup 1.0000x reference)
//
#include <hip/hip_runtime.h>

typedef __attribute__((ext_vector_type(8))) short bf16x8;
typedef __attribute__((ext_vector_type(4))) float f32x4;
typedef __attribute__((ext_vector_type(4))) int   i32x4;

#define NROWS     131072
#define KCODES    1024
#define OUT_ELEMS 8388608
#define NBLK      1024              // 128 rows per block, one generation
#define MAGICF    12582912.0f       // 1.5 * 2^23
#define MARGIN    240               // key-quanta (2^-16 t-units); >= 2x worst-case screen err (~80)
#define XSTRIDE   65                // x_lds row stride (gcd(65,32)=1 -> spread banks)
// d_ws layout
#define WS_PART   0                 // 1024 doubles (8 KB)
#define WS_SE     (8*1024)          // 1024 f32 exact ||e||^2
#define WS_SEMG   (12*1024)         // 1024 f32: MAGICF + se*2^16 (MFMA acc-init)
#define WS_BPREP  (16*1024)         // 64 chunks * 2 frags * 64 lanes * 16B = 128 KB

// numpy pairwise sum pattern for n=64 (exact fp32; round-2 verified).
__device__ __forceinline__ float pairwise64_sq(const float* __restrict__ v) {
#pragma clang fp contract(off)
    float r[8];
#pragma unroll
    for (int j = 0; j < 8; ++j) r[j] = v[j] * v[j];
#pragma unroll
    for (int i = 8; i < 64; i += 8) {
#pragma unroll
        for (int j = 0; j < 8; ++j) r[j] += v[i + j] * v[i + j];
    }
    return ((r[0] + r[1]) + (r[2] + r[3])) + ((r[4] + r[5]) + (r[6] + r[7]));
}

__device__ __forceinline__ int med3i(int a, int b, int c) {
    int mn = min(a, b), mx = max(a, b);
    return max(mn, min(mx, c));   // v_med3_i32
}

__device__ __forceinline__ unsigned short rne_bf16(float v) {
    unsigned u = __float_as_uint(v);
    return (unsigned short)((u + 0x7fffu + ((u >> 16) & 1u)) >> 16);
}

// One thread per code: exact se; acc-init MAGICF + se*2^16; single-split bf16
// B frags scaled 2^8 (RNE). chunk c=k>>4, frag f=khalf, lane l=g*16+(k&15).
__global__ __launch_bounds__(256) void vq_prep(
    const float* __restrict__ emb, float* __restrict__ se,
    float* __restrict__ semg, unsigned short* __restrict__ bprep)
{
#pragma clang fp contract(off)
    const int k = blockIdx.x * 256 + threadIdx.x;
    if (k >= KCODES) return;
    const float* e = emb + (k << 6);
    float s = pairwise64_sq(e);
    se[k]   = s;
    semg[k] = MAGICF + s * 65536.0f;

    const int c = k >> 4, slot = k & 15;
#pragma unroll
    for (int f = 0; f < 2; ++f) {
#pragma unroll
        for (int g = 0; g < 4; ++g) {
            unsigned short h[8];
#pragma unroll
            for (int j = 0; j < 8; ++j)
                h[j] = rne_bf16(e[f * 32 + g * 8 + j] * 256.0f);
            int4 w;
            w.x = h[0] | (h[1] << 16); w.y = h[2] | (h[3] << 16);
            w.z = h[4] | (h[5] << 16); w.w = h[6] | (h[7] << 16);
            *reinterpret_cast<int4*>(bprep + (((c * 2 + f) * 64 + (g * 16 + slot)) << 3)) = w;
        }
    }
}

// min-waves=3, NOT 4 (round-8: 4 clamps to 64-VGPR granule -> hot-loop spill).
__global__ __launch_bounds__(256, 3) void vq_main(
    const float* __restrict__ lat, const float* __restrict__ emb,
    const float* __restrict__ se_g, const float* __restrict__ semg_g,
    const unsigned short* __restrict__ bprep,
    float* __restrict__ out, double* __restrict__ partials)
{
#pragma clang fp contract(off)
    __shared__ float  x_lds[128 * XSTRIDE];   // 33.3 KB
    __shared__ int    cand_lds[128][8];       // 4 KB: in-margin candidate codes
    __shared__ int    cnt_lds[128];
    __shared__ int    idx_lds[128];
    __shared__ double wsum[4];

    const int tid = threadIdx.x, l = tid & 63, wv = tid >> 6;
    const int blk = blockIdx.x;
    const int n0 = blk * 128, b = n0 >> 12, hw0 = n0 & 4095;
    const float* latb = lat + ((size_t)b << 18) + hw0;   // elem: latb[(d<<12)+row]

    // ---- stage x: float4 along hw (coalesced) ----
    {
        const float4* lat4 = reinterpret_cast<const float4*>(latb);
#pragma unroll
        for (int it = 0; it < 8; ++it) {
            int idx = it * 256 + tid;        // 0..2047
            int d = idx >> 5, hwg = idx & 31;
            float4 v = lat4[(size_t)d * 1024 + hwg];
            int row = hwg * 4;
            x_lds[(row + 0) * XSTRIDE + d] = v.x;
            x_lds[(row + 1) * XSTRIDE + d] = v.y;
            x_lds[(row + 2) * XSTRIDE + d] = v.z;
            x_lds[(row + 3) * XSTRIDE + d] = v.w;
        }
    }
    __syncthreads();

    // ---- A fragments from LDS: -2x * 2^8, RNE bf16 (row=l&15, k=(l>>4)*8+j) ----
    bf16x8 afrag[2][2];   // [tile][khalf]
    {
        const int arow = l & 15, kb = (l >> 4) << 3;
#pragma unroll
        for (int T = 0; T < 2; ++T) {
            const float* xr = x_lds + (wv * 32 + T * 16 + arow) * XSTRIDE;
#pragma unroll
            for (int kh = 0; kh < 2; ++kh) {
                bf16x8 f;
#pragma unroll
                for (int j = 0; j < 8; ++j)
                    f[j] = (short)rne_bf16(xr[kh * 32 + kb + j] * -512.0f);
                afrag[T][kh] = f;
            }
        }
    }

    // ---- sweep 64 chunks: acc-init = magic+se*2^16, 4 MFMA/chunk,
    //      key = (bits(acc)<<10)|code, top-3 per (T,reg); prefetch depth 2 ----
    int m1[2][4], m2[2][4], m3[2][4];
#pragma unroll
    for (int T = 0; T < 2; ++T)
#pragma unroll
        for (int r = 0; r < 4; ++r) { m1[T][r] = m2[T][r] = m3[T][r] = 0x7fffffff; }

    const i32x4* bp = reinterpret_cast<const i32x4*>(bprep);
    i32x4 bb0[4], bb1[4];
    float sb[4];
    bb0[0] = bp[l];        bb1[0] = bp[64 + l];        sb[0] = semg_g[l & 15];
    bb0[1] = bp[128 + l];  bb1[1] = bp[192 + l];       sb[1] = semg_g[16 + (l & 15)];

#pragma unroll 4
    for (int c = 0; c < 64; ++c) {
        const int cs = c & 3;
        if (c + 2 < 64) {
            const int ps = (c + 2) & 3;
            bb0[ps] = bp[(c + 2) * 128 + l];
            bb1[ps] = bp[(c + 2) * 128 + 64 + l];
            sb[ps]  = semg_g[(c + 2) * 16 + (l & 15)];
        }
        bf16x8 b0 = __builtin_bit_cast(bf16x8, bb0[cs]);
        bf16x8 b1 = __builtin_bit_cast(bf16x8, bb1[cs]);
        const float sv = sb[cs];
        const unsigned code0 = (unsigned)((c << 4) + (l & 15));
#pragma unroll
        for (int T = 0; T < 2; ++T) {
            f32x4 acc = {sv, sv, sv, sv};
            acc = __builtin_amdgcn_mfma_f32_16x16x32_bf16(afrag[T][0], b0, acc, 0, 0, 0);
            acc = __builtin_amdgcn_mfma_f32_16x16x32_bf16(afrag[T][1], b1, acc, 0, 0, 0);
#pragma unroll
            for (int r = 0; r < 4; ++r) {
                // acc in [2^23,2^24): low mantissa == (t*2^16) mod 2^22;
                // <<10 is signed-monotone for |t*2^16| < 2^21.
                int key = (int)((__float_as_uint(acc[r]) << 10) | code0);
                int n1 = min(key, m1[T][r]);
                int n2 = med3i(key, m1[T][r], m2[T][r]);
                int n3 = med3i(max(key, m1[T][r]), m2[T][r], m3[T][r]);
                m1[T][r] = n1; m2[T][r] = n2; m3[T][r] = n3;
            }
        }
    }

    // ---- candidate compaction: row-min + ballot prefix into cand_lds ----
    {
        const int g = l >> 4, cl = l & 15;
#pragma unroll
        for (int T = 0; T < 2; ++T) {
#pragma unroll
            for (int r = 0; r < 4; ++r) {
                const int row = wv * 32 + T * 16 + (g << 2) + r;
                int rm = m1[T][r];
#pragma unroll
                for (int off = 1; off < 16; off <<= 1)
                    rm = min(rm, __shfl_xor(rm, off, 64));
                const int lim = rm + (MARGIN << 10) + 1023;
                int cnt = 0;
#pragma unroll
                for (int kk = 0; kk < 3; ++kk) {
                    int key = (kk == 0) ? m1[T][r] : (kk == 1) ? m2[T][r] : m3[T][r];
                    bool pred = (key <= lim);
                    unsigned long long mask = __ballot(pred);
                    unsigned ml = (unsigned)((mask >> (g * 16)) & 0xFFFFull);
                    if (pred) {
                        int pos = cnt + __popc(ml & ((1u << cl) - 1u));
                        if (pos < 8) cand_lds[row][pos] = key & 1023;
                    }
                    cnt += __popc(ml);
                }
                if (cl == 0) cnt_lds[row] = cnt;
            }
        }
    }
    __syncthreads();

    // ---- finalize: one lane per row (128 lanes), exact fp32 re-check ----
    if (tid < 128) {
        const int row = tid;
        const float* xr = x_lds + row * XSTRIDE;
        const float sx = pairwise64_sq(xr);
        const int cnt = cnt_lds[row];
        float bestd = 3.4e38f; int besti = KCODES;
        if (cnt <= 8) {
#pragma unroll 1
            for (int i = 0; i < cnt; ++i) {
                int code = cand_lds[row][i];
                const float* e = emb + (code << 6);
                float gacc = 0.0f;
#pragma unroll
                for (int d = 0; d < 64; ++d)
                    gacc = fmaf(xr[d], e[d], gacc);
                float s_   = sx + se_g[code];   // fl32
                float dist = s_ - 2.0f * gacc;  // 2g exact; fl32 subtract
                if (dist < bestd || (dist == bestd && code < besti)) { bestd = dist; besti = code; }
            }
        } else {
            // overflow fallback (P ~ 1e-12): exact scan of all codes
#pragma unroll 1
            for (int code = 0; code < KCODES; ++code) {
                const float* e = emb + (code << 6);
                float gacc = 0.0f;
#pragma unroll
                for (int d = 0; d < 64; ++d)
                    gacc = fmaf(xr[d], e[d], gacc);
                float s_   = sx + se_g[code];
                float dist = s_ - 2.0f * gacc;
                if (dist < bestd) { bestd = dist; besti = code; }
            }
        }
        idx_lds[row] = besti;
        out[OUT_ELEMS + 1 + (size_t)n0 + row] = (float)besti;
    }
    __syncthreads();

    // ---- epilogue: q_st (coalesced), loss partial ----
    double lsum = 0.0;
    {
        const float aq = 1.0f / 8388608.0f;   // 2^-23 exactly
        const int row = tid & 127, dh = (tid >> 7) * 32;
        const int code = idx_lds[row];
        const float4* eq4 = reinterpret_cast<const float4*>(emb + (code << 6) + dh);
        const float* xr = x_lds + row * XSTRIDE;
        float* ob = out + ((size_t)b << 18) + hw0 + row;
#pragma unroll
        for (int qq = 0; qq < 8; ++qq) {
            float4 qv = eq4[qq];
            float qa[4] = {qv.x, qv.y, qv.z, qv.w};
#pragma unroll
            for (int u = 0; u < 4; ++u) {
                int d = dh + qq * 4 + u;
                float xv = xr[d];
                float qd = qa[u];
                float v  = (xv + aq * qd) + ((1.0f - aq) * qd - xv);
                ob[(size_t)d << 12] = v;
                float diff = qd - xv;
                lsum += (double)diff * (double)diff;
            }
        }
    }

#pragma unroll
    for (int off = 32; off > 0; off >>= 1) lsum += __shfl_down(lsum, off, 64);
    if (l == 0) wsum[wv] = lsum;
    __syncthreads();
    if (tid == 0) partials[blk] = (wsum[0] + wsum[1]) + (wsum[2] + wsum[3]);
}

__global__ __launch_bounds__(512) void vq_finish(
    const double* __restrict__ partials, float* __restrict__ out)
{
    __shared__ double lds[8];
    const int t = threadIdx.x;
    double s = partials[t] + partials[t + 512];
#pragma unroll
    for (int off = 32; off > 0; off >>= 1) s += __shfl_down(s, off, 64);
    if ((t & 63) == 0) lds[t >> 6] = s;
    __syncthreads();
    if (t == 0) {
        double tot = 0.0;
#pragma unroll
        for (int i = 0; i < 8; ++i) tot += lds[i];
        out[OUT_ELEMS] = (float)(0.75 * tot / (double)OUT_ELEMS);
    }
}

extern "C" void kernel_launch(void* const* d_in, const int* in_sizes, int n_in,
                              void* d_out, int out_size, void* d_ws, size_t ws_size,
                              hipStream_t stream)
{
    const float* lat = (const float*)d_in[0];
    const float* emb = (const float*)d_in[1];
    float* out = (float*)d_out;
    char* ws = (char*)d_ws;

    double* partials      = (double*)(ws + WS_PART);
    float* se             = (float*)(ws + WS_SE);
    float* semg           = (float*)(ws + WS_SEMG);
    unsigned short* bprep = (unsigned short*)(ws + WS_BPREP);

    vq_prep<<<dim3(4),    dim3(256), 0, stream>>>(emb, se, semg, bprep);
    vq_main<<<dim3(NBLK), dim3(256), 0, stream>>>(lat, emb, se, semg, bprep, out, partials);
    vq_finish<<<dim3(1),  dim3(512), 0, stream>>>(partials, out);
}

// Round 12
// 502.775 us; speedup vs baseline: 1.0079x; 1.0079x over previous
//
#include <hip/hip_runtime.h>

typedef __attribute__((ext_vector_type(8))) short bf16x8;
typedef __attribute__((ext_vector_type(4))) float f32x4;
typedef __attribute__((ext_vector_type(4))) int   i32x4;

#define NROWS     131072
#define KCODES    1024
#define OUT_ELEMS 8388608
#define NBLK      1024              // 128 rows/block; 4 blocks/CU = one generation
#define MAGICF    12582912.0f       // 1.5 * 2^23
#define MARGIN    240               // key-quanta (2^-16 t-units); >= 2x worst-case screen err
#define XSTRIDE   65
// d_ws layout
#define WS_PART   0                 // 1024 doubles (8 KB)
#define WS_SE     (8*1024)          // 1024 f32 exact ||e||^2
#define WS_SEMG   (12*1024)         // 1024 f32: MAGICF + se*2^16 (MFMA acc-init)
#define WS_BPREP  (16*1024)         // 64 chunks * 2 frags * 64 lanes * 16B = 128 KB

// numpy pairwise sum pattern for n=64 (exact fp32; round-2 verified).
__device__ __forceinline__ float pairwise64_sq(const float* __restrict__ v) {
#pragma clang fp contract(off)
    float r[8];
#pragma unroll
    for (int j = 0; j < 8; ++j) r[j] = v[j] * v[j];
#pragma unroll
    for (int i = 8; i < 64; i += 8) {
#pragma unroll
        for (int j = 0; j < 8; ++j) r[j] += v[i + j] * v[i + j];
    }
    return ((r[0] + r[1]) + (r[2] + r[3])) + ((r[4] + r[5]) + (r[6] + r[7]));
}

__device__ __forceinline__ int med3i(int a, int b, int c) {
    int mn = min(a, b), mx = max(a, b);
    return max(mn, min(mx, c));   // v_med3_i32
}

__device__ __forceinline__ unsigned short rne_bf16(float v) {
    unsigned u = __float_as_uint(v);
    return (unsigned short)((u + 0x7fffu + ((u >> 16) & 1u)) >> 16);
}

__global__ __launch_bounds__(256) void vq_prep(
    const float* __restrict__ emb, float* __restrict__ se,
    float* __restrict__ semg, unsigned short* __restrict__ bprep)
{
#pragma clang fp contract(off)
    const int k = blockIdx.x * 256 + threadIdx.x;
    if (k >= KCODES) return;
    const float* e = emb + (k << 6);
    float s = pairwise64_sq(e);
    se[k]   = s;
    semg[k] = MAGICF + s * 65536.0f;

    const int c = k >> 4, slot = k & 15;
#pragma unroll
    for (int f = 0; f < 2; ++f) {
#pragma unroll
        for (int g = 0; g < 4; ++g) {
            unsigned short h[8];
#pragma unroll
            for (int j = 0; j < 8; ++j)
                h[j] = rne_bf16(e[f * 32 + g * 8 + j] * 256.0f);
            int4 w;
            w.x = h[0] | (h[1] << 16); w.y = h[2] | (h[3] << 16);
            w.z = h[4] | (h[5] << 16); w.w = h[6] | (h[7] << 16);
            *reinterpret_cast<int4*>(bprep + (((c * 2 + f) * 64 + (g * 16 + slot)) << 3)) = w;
        }
    }
}

// (256,2): r7's proven regalloc regime. NEVER min-waves=4 (r8: 64-VGPR clamp
// -> hot-loop spill). All pipeline state in NAMED scalars (r10/r11: runtime-
// indexed arrays were demoted to scratch, VGPR 52/56, 4x regression).
__global__ __launch_bounds__(256, 2) void vq_main(
    const float* __restrict__ lat, const float* __restrict__ emb,
    const float* __restrict__ se_g, const float* __restrict__ semg_g,
    const unsigned short* __restrict__ bprep,
    float* __restrict__ out, double* __restrict__ partials)
{
#pragma clang fp contract(off)
    __shared__ float  x_lds[128 * XSTRIDE];   // 32.5 KB
    __shared__ int    cand_lds[128][8];       // 4 KB
    __shared__ int    cnt_lds[128];
    __shared__ int    idx_lds[128];
    __shared__ double wsum[4];

    const int tid = threadIdx.x, l = tid & 63, wv = tid >> 6;
    const int blk = blockIdx.x;
    const int n0 = blk * 128, b = n0 >> 12, hw0 = n0 & 4095;
    const float* latb = lat + ((size_t)b << 18) + hw0;   // elem: latb[(d<<12)+row]

    // ---- stage x: float4 along hw (coalesced) ----
    {
        const float4* lat4 = reinterpret_cast<const float4*>(latb);
#pragma unroll
        for (int it = 0; it < 8; ++it) {
            int idx = it * 256 + tid;        // 0..2047
            int d = idx >> 5, hwg = idx & 31;
            float4 v = lat4[(size_t)d * 1024 + hwg];
            int row = hwg * 4;
            x_lds[(row + 0) * XSTRIDE + d] = v.x;
            x_lds[(row + 1) * XSTRIDE + d] = v.y;
            x_lds[(row + 2) * XSTRIDE + d] = v.z;
            x_lds[(row + 3) * XSTRIDE + d] = v.w;
        }
    }
    __syncthreads();

    // ---- A fragments from LDS: -2x * 2^8, RNE bf16 (row=l&15, k=(l>>4)*8+j) ----
    bf16x8 a00, a01, a10, a11;   // [tile T][khalf]
    {
        const int arow = l & 15, kb = (l >> 4) << 3;
        const float* xr0 = x_lds + (wv * 32 + arow) * XSTRIDE;
        const float* xr1 = x_lds + (wv * 32 + 16 + arow) * XSTRIDE;
        bf16x8 f;
#pragma unroll
        for (int j = 0; j < 8; ++j) f[j] = (short)rne_bf16(xr0[kb + j]      * -512.0f);
        a00 = f;
#pragma unroll
        for (int j = 0; j < 8; ++j) f[j] = (short)rne_bf16(xr0[32 + kb + j] * -512.0f);
        a01 = f;
#pragma unroll
        for (int j = 0; j < 8; ++j) f[j] = (short)rne_bf16(xr1[kb + j]      * -512.0f);
        a10 = f;
#pragma unroll
        for (int j = 0; j < 8; ++j) f[j] = (short)rne_bf16(xr1[32 + kb + j] * -512.0f);
        a11 = f;
    }

    // ---- sweep: 64 chunks, hand-unrolled x2, 2-deep pipeline in NAMED vars ----
    int m1_00, m1_01, m1_02, m1_03, m2_00, m2_01, m2_02, m2_03, m3_00, m3_01, m3_02, m3_03;
    int m1_10, m1_11, m1_12, m1_13, m2_10, m2_11, m2_12, m2_13, m3_10, m3_11, m3_12, m3_13;
    m1_00 = m1_01 = m1_02 = m1_03 = m2_00 = m2_01 = m2_02 = m2_03 = m3_00 = m3_01 = m3_02 = m3_03 = 0x7fffffff;
    m1_10 = m1_11 = m1_12 = m1_13 = m2_10 = m2_11 = m2_12 = m2_13 = m3_10 = m3_11 = m3_12 = m3_13 = 0x7fffffff;

    const i32x4* bp = reinterpret_cast<const i32x4*>(bprep);
    const int scol = l & 15;

    // slot0 <- chunk 0, slot1 <- chunk 1
    i32x4 s0b0 = bp[l],        s0b1 = bp[64 + l];
    float s0sv = semg_g[scol];
    i32x4 s1b0 = bp[128 + l],  s1b1 = bp[192 + l];
    float s1sv = semg_g[16 + scol];

#define TOP3(key, M1, M2, M3)                                   \
    {   int n1_ = min(key, M1);                                 \
        int n2_ = med3i(key, M1, M2);                           \
        int n3_ = med3i(max(key, M1), M2, M3);                  \
        M1 = n1_; M2 = n2_; M3 = n3_; }

#define SWEEP_BODY(B0, B1, SV, CC)                                                     \
    {   bf16x8 b0_ = __builtin_bit_cast(bf16x8, B0);                                   \
        bf16x8 b1_ = __builtin_bit_cast(bf16x8, B1);                                   \
        const unsigned code0_ = (unsigned)(((CC) << 4) + scol);                        \
        f32x4 acc0 = {SV, SV, SV, SV};                                                 \
        acc0 = __builtin_amdgcn_mfma_f32_16x16x32_bf16(a00, b0_, acc0, 0, 0, 0);       \
        acc0 = __builtin_amdgcn_mfma_f32_16x16x32_bf16(a01, b1_, acc0, 0, 0, 0);       \
        f32x4 acc1 = {SV, SV, SV, SV};                                                 \
        acc1 = __builtin_amdgcn_mfma_f32_16x16x32_bf16(a10, b0_, acc1, 0, 0, 0);       \
        acc1 = __builtin_amdgcn_mfma_f32_16x16x32_bf16(a11, b1_, acc1, 0, 0, 0);       \
        int k0, k1, k2, k3;                                                            \
        k0 = (int)((__float_as_uint(acc0[0]) << 10) | code0_); TOP3(k0, m1_00, m2_00, m3_00); \
        k1 = (int)((__float_as_uint(acc0[1]) << 10) | code0_); TOP3(k1, m1_01, m2_01, m3_01); \
        k2 = (int)((__float_as_uint(acc0[2]) << 10) | code0_); TOP3(k2, m1_02, m2_02, m3_02); \
        k3 = (int)((__float_as_uint(acc0[3]) << 10) | code0_); TOP3(k3, m1_03, m2_03, m3_03); \
        k0 = (int)((__float_as_uint(acc1[0]) << 10) | code0_); TOP3(k0, m1_10, m2_10, m3_10); \
        k1 = (int)((__float_as_uint(acc1[1]) << 10) | code0_); TOP3(k1, m1_11, m2_11, m3_11); \
        k2 = (int)((__float_as_uint(acc1[2]) << 10) | code0_); TOP3(k2, m1_12, m2_12, m3_12); \
        k3 = (int)((__float_as_uint(acc1[3]) << 10) | code0_); TOP3(k3, m1_13, m2_13, m3_13); }

#pragma unroll 1
    for (int c = 0; c < 64; c += 2) {
        // even: consume slot0 (chunk c), reload slot0 <- chunk c+2
        SWEEP_BODY(s0b0, s0b1, s0sv, c);
        if (c + 2 < 64) {
            s0b0 = bp[(c + 2) * 128 + l];
            s0b1 = bp[(c + 2) * 128 + 64 + l];
            s0sv = semg_g[(c + 2) * 16 + scol];
        }
        // odd: consume slot1 (chunk c+1), reload slot1 <- chunk c+3
        SWEEP_BODY(s1b0, s1b1, s1sv, c + 1);
        if (c + 3 < 64) {
            s1b0 = bp[(c + 3) * 128 + l];
            s1b1 = bp[(c + 3) * 128 + 64 + l];
            s1sv = semg_g[(c + 3) * 16 + scol];
        }
    }
#undef SWEEP_BODY
#undef TOP3

    // ---- candidate compaction: row-min + ballot prefix into cand_lds ----
    {
        const int g = l >> 4, cl = l & 15;
#pragma unroll
        for (int T = 0; T < 2; ++T) {
#pragma unroll
            for (int r = 0; r < 4; ++r) {
                int k1 = (T == 0) ? ((r == 0) ? m1_00 : (r == 1) ? m1_01 : (r == 2) ? m1_02 : m1_03)
                                  : ((r == 0) ? m1_10 : (r == 1) ? m1_11 : (r == 2) ? m1_12 : m1_13);
                int k2 = (T == 0) ? ((r == 0) ? m2_00 : (r == 1) ? m2_01 : (r == 2) ? m2_02 : m2_03)
                                  : ((r == 0) ? m2_10 : (r == 1) ? m2_11 : (r == 2) ? m2_12 : m2_13);
                int k3 = (T == 0) ? ((r == 0) ? m3_00 : (r == 1) ? m3_01 : (r == 2) ? m3_02 : m3_03)
                                  : ((r == 0) ? m3_10 : (r == 1) ? m3_11 : (r == 2) ? m3_12 : m3_13);
                const int row = wv * 32 + T * 16 + (g << 2) + r;
                int rm = k1;
#pragma unroll
                for (int off = 1; off < 16; off <<= 1)
                    rm = min(rm, __shfl_xor(rm, off, 64));
                const int lim = rm + (MARGIN << 10) + 1023;
                int cnt = 0;
#pragma unroll
                for (int kk = 0; kk < 3; ++kk) {
                    int key = (kk == 0) ? k1 : (kk == 1) ? k2 : k3;
                    bool pred = (key <= lim);
                    unsigned long long mask = __ballot(pred);
                    unsigned ml = (unsigned)((mask >> (g * 16)) & 0xFFFFull);
                    if (pred) {
                        int pos = cnt + __popc(ml & ((1u << cl) - 1u));
                        if (pos < 8) cand_lds[row][pos] = key & 1023;
                    }
                    cnt += __popc(ml);
                }
                if (cl == 0) cnt_lds[row] = cnt;
            }
        }
    }
    __syncthreads();

    // ---- finalize: one lane per row (128-wide), exact fp32 re-check ----
    if (tid < 128) {
        const int row = tid;
        const float* xr = x_lds + row * XSTRIDE;
        const float sx = pairwise64_sq(xr);
        const int cnt = cnt_lds[row];
        float bestd = 3.4e38f; int besti = KCODES;
        if (cnt <= 8) {
#pragma unroll 1
            for (int i = 0; i < cnt; ++i) {
                int code = cand_lds[row][i];
                const float* e = emb + (code << 6);
                float gacc = 0.0f;
#pragma unroll
                for (int d = 0; d < 64; ++d)
                    gacc = fmaf(xr[d], e[d], gacc);
                float s_   = sx + se_g[code];   // fl32
                float dist = s_ - 2.0f * gacc;  // 2g exact; fl32 subtract
                if (dist < bestd || (dist == bestd && code < besti)) { bestd = dist; besti = code; }
            }
        } else {
            // overflow fallback (P ~ 1e-12): exact scan of all codes
#pragma unroll 1
            for (int code = 0; code < KCODES; ++code) {
                const float* e = emb + (code << 6);
                float gacc = 0.0f;
#pragma unroll
                for (int d = 0; d < 64; ++d)
                    gacc = fmaf(xr[d], e[d], gacc);
                float s_   = sx + se_g[code];
                float dist = s_ - 2.0f * gacc;
                if (dist < bestd) { bestd = dist; besti = code; }
            }
        }
        idx_lds[row] = besti;
        out[OUT_ELEMS + 1 + (size_t)n0 + row] = (float)besti;
    }
    __syncthreads();

    // ---- epilogue: q_st (coalesced), loss partial ----
    double lsum = 0.0;
    {
        const float aq = 1.0f / 8388608.0f;   // 2^-23 exactly
        const int row = tid & 127, dh = (tid >> 7) * 32;
        const int code = idx_lds[row];
        const float4* eq4 = reinterpret_cast<const float4*>(emb + (code << 6) + dh);
        const float* xr = x_lds + row * XSTRIDE;
        float* ob = out + ((size_t)b << 18) + hw0 + row;
#pragma unroll
        for (int qq = 0; qq < 8; ++qq) {
            float4 qv = eq4[qq];
            float qa[4] = {qv.x, qv.y, qv.z, qv.w};
#pragma unroll
            for (int u = 0; u < 4; ++u) {
                int d = dh + qq * 4 + u;
                float xv = xr[d];
                float qd = qa[u];
                float v  = (xv + aq * qd) + ((1.0f - aq) * qd - xv);
                ob[(size_t)d << 12] = v;
                float diff = qd - xv;
                lsum += (double)diff * (double)diff;
            }
        }
    }

#pragma unroll
    for (int off = 32; off > 0; off >>= 1) lsum += __shfl_down(lsum, off, 64);
    if (l == 0) wsum[wv] = lsum;
    __syncthreads();
    if (tid == 0) partials[blk] = (wsum[0] + wsum[1]) + (wsum[2] + wsum[3]);
}

__global__ __launch_bounds__(512) void vq_finish(
    const double* __restrict__ partials, float* __restrict__ out)
{
    __shared__ double lds[8];
    const int t = threadIdx.x;
    double s = partials[t] + partials[t + 512];
#pragma unroll
    for (int off = 32; off > 0; off >>= 1) s += __shfl_down(s, off, 64);
    if ((t & 63) == 0) lds[t >> 6] = s;
    __syncthreads();
    if (t == 0) {
        double tot = 0.0;
#pragma unroll
        for (int i = 0; i < 8; ++i) tot += lds[i];
        out[OUT_ELEMS] = (float)(0.75 * tot / (double)OUT_ELEMS);
    }
}

extern "C" void kernel_launch(void* const* d_in, const int* in_sizes, int n_in,
                              void* d_out, int out_size, void* d_ws, size_t ws_size,
                              hipStream_t stream)
{
    const float* lat = (const float*)d_in[0];
    const float* emb = (const float*)d_in[1];
    float* out = (float*)d_out;
    char* ws = (char*)d_ws;

    double* partials      = (double*)(ws + WS_PART);
    float* se             = (float*)(ws + WS_SE);
    float* semg           = (float*)(ws + WS_SEMG);
    unsigned short* bprep = (unsigned short*)(ws + WS_BPREP);

    vq_prep<<<dim3(4),    dim3(256), 0, stream>>>(emb, se, semg, bprep);
    vq_main<<<dim3(NBLK), dim3(256), 0, stream>>>(lat, emb, se, semg, bprep, out, partials);
    vq_finish<<<dim3(1),  dim3(512), 0, stream>>>(partials, out);
}